// Round 8
// baseline (218.940 us; speedup 1.0000x reference)
//
#include <hip/hip_runtime.h>

#define N_TOK 4096
#define C_IN 256
#define CI_ 128

typedef unsigned short u16;
typedef unsigned int   u32;
typedef __attribute__((ext_vector_type(8))) short bf16x8;
typedef __attribute__((ext_vector_type(4))) float f32x4;

// ---- bf16 helpers ----
__device__ __forceinline__ float lo16f(u32 u){ union{u32 i; float f;} c; c.i = u << 16; return c.f; }
__device__ __forceinline__ float hi16f(u32 u){ union{u32 i; float f;} c; c.i = u & 0xffff0000u; return c.f; }
__device__ __forceinline__ void bf8f(const uint4 u, float* f){
    f[0]=lo16f(u.x); f[1]=hi16f(u.x); f[2]=lo16f(u.y); f[3]=hi16f(u.y);
    f[4]=lo16f(u.z); f[5]=hi16f(u.z); f[6]=lo16f(u.w); f[7]=hi16f(u.w);
}
__device__ __forceinline__ float bf1f(u16 v){ union{u32 i; float f;} c; c.i = ((u32)v)<<16; return c.f; }
__device__ __forceinline__ u16 f2bf(float f){
    union{float f; u32 i;} c; c.f = f;
    u32 i = c.i;
    u32 r = (i + 0x7fffu + ((i >> 16) & 1u)) >> 16;   // RNE
    return (u16)r;
}
__device__ __forceinline__ u32 packbf(float a, float b){
    return (u32)f2bf(a) | ((u32)f2bf(b) << 16);
}

__device__ __forceinline__ void load8(const void* base, size_t idx, int flag, float* f){
    if (flag) {
        const float* p = (const float*)base + idx;
        *(float4*)&f[0] = *(const float4*)p;
        *(float4*)&f[4] = *(const float4*)(p + 4);
    } else {
        uint4 u = *(const uint4*)((const u16*)base + idx);
        bf8f(u, f);
    }
}
__device__ __forceinline__ void load4(const void* base, size_t idx, int flag, float* f){
    if (flag) {
        float4 v = *(const float4*)((const float*)base + idx);
        f[0]=v.x; f[1]=v.y; f[2]=v.z; f[3]=v.w;
    } else {
        uint2 u = *(const uint2*)((const u16*)base + idx);
        f[0]=lo16f(u.x); f[1]=hi16f(u.x); f[2]=lo16f(u.y); f[3]=hi16f(u.y);
    }
}

// async global->LDS DMA, 16B per lane, dest = wave-uniform base + lane*16
__device__ __forceinline__ void dma16(const u16* g, char* l){
    __builtin_amdgcn_global_load_lds(
        (const __attribute__((address_space(1))) u32*)g,
        (__attribute__((address_space(3))) u32*)l, 16, 0, 0);
}

// ===================== param canonicalize (+flag inline, +stats zero) =====================
__global__ __launch_bounds__(256) void convert_params_kernel(
    const void* wg, const void* wt, const void* wp, const void* wo,
    const void* bg, const void* bt, const void* bp, const void* bo,
    const void* gm, const void* bt2,
    int* __restrict__ flagp, float* __restrict__ canon, u16* __restrict__ canon_bf,
    float* __restrict__ stats)
{
    __shared__ int sflag;
    const int tid = threadIdx.x;
    if (tid < 64) {
        int cnt = 0;
        const u16* wgp = (const u16*)wg;
        for (int i = tid; i < 256; i += 64) {
            u16 v = wgp[2 * i];
            if (((v >> 7) & 0xFF) >= 128) cnt++;
        }
        #pragma unroll
        for (int off = 32; off; off >>= 1) cnt += __shfl_down(cnt, off);
        if (tid == 0) sflag = (cnt >= 8) ? 1 : 0;
    }
    __syncthreads();
    const int f = sflag;
    if (blockIdx.x == 0 && tid == 0) *flagp = f;

    int idx = blockIdx.x * 256 + tid;
    if (idx >= 132224) {
        int j = idx - 132224;
        if (j < 8192) stats[j] = 0.f;
        return;
    }
    const void* src; int loc;
    if      (idx < 32768)  { src = wg;  loc = idx; }
    else if (idx < 65536)  { src = wt;  loc = idx - 32768; }
    else if (idx < 98304)  { src = wp;  loc = idx - 65536; }
    else if (idx < 131072) { src = wo;  loc = idx - 98304; }
    else if (idx < 131200) { src = bg;  loc = idx - 131072; }
    else if (idx < 131328) { src = bt;  loc = idx - 131200; }
    else if (idx < 131456) { src = bp;  loc = idx - 131328; }
    else if (idx < 131712) { src = bo;  loc = idx - 131456; }
    else if (idx < 131968) { src = gm;  loc = idx - 131712; }
    else                   { src = bt2; loc = idx - 131968; }
    float v = f ? ((const float*)src)[loc] : bf1f(((const u16*)src)[loc]);
    canon[idx] = v;
    if (idx < 131072) canon_bf[idx] = f2bf(v);
}

// =====================================================================
// Kernel X: x [b][k][n] (fp32 or bf16) -> xbfT [b][n][k] bf16
// =====================================================================
__global__ __launch_bounds__(256) void xpose_kernel(
    const void* __restrict__ x, const int* __restrict__ flagp, u16* __restrict__ xbfT)
{
    __shared__ u16 t[64][72];
    const int flag = *flagp;
    const int b = blockIdx.z, k0 = blockIdx.y * 64, n0 = blockIdx.x * 64;
    const int tid = threadIdx.x;
    const size_t xb = (size_t)b * C_IN * N_TOK;
    {
        int kk = tid >> 4, n4 = (tid & 15) * 4;
        #pragma unroll
        for (int i = 0; i < 4; ++i) {
            float f[4];
            load4(x, xb + (size_t)(k0 + kk + i * 16) * N_TOK + n0 + n4, flag, f);
            #pragma unroll
            for (int j = 0; j < 4; ++j) t[n4 + j][kk + i * 16] = f2bf(f[j]);
        }
    }
    __syncthreads();
    {
        int kq = tid & 3, n = tid >> 2;
        u16* dst = &xbfT[((size_t)b * N_TOK + n0 + n) * C_IN + k0 + kq * 16];
        *(uint4*)(dst + 0) = *(const uint4*)&t[n][kq * 16];
        *(uint4*)(dst + 8) = *(const uint4*)&t[n][kq * 16 + 8];
    }
}

// =====================================================================
// Kernel A: MFMA projections, barrier-free K-loop (direct frag loads).
// wave w: r in [48w, 48w+48). n-tile 64.
// =====================================================================
__global__ __launch_bounds__(512) void proj_kernel(
    const u16* __restrict__ xbfT, const float* __restrict__ canon,
    const u16* __restrict__ wbf,
    u16* __restrict__ gbuf, u16* __restrict__ tbufT, u16* __restrict__ pbufT)
{
    __shared__ __align__(16) u16 plds[64 * 400];
    const int b  = blockIdx.y;
    const int n0 = blockIdx.x * 64;
    const int tid = threadIdx.x;
    const int w    = tid >> 6;
    const int lane = tid & 63;
    const int col  = lane & 15;
    const int quad = lane >> 4;
    const int rw   = w * 48;
    const size_t bN = (size_t)b * N_TOK;

    f32x4 acc[3][4];
    #pragma unroll
    for (int i = 0; i < 3; ++i)
        #pragma unroll
        for (int j = 0; j < 4; ++j) acc[i][j] = (f32x4){0.f,0.f,0.f,0.f};

    #pragma unroll
    for (int kc = 0; kc < 8; ++kc) {
        bf16x8 bfr[4];
        #pragma unroll
        for (int nf = 0; nf < 4; ++nf)
            bfr[nf] = *(const bf16x8*)&xbfT[(bN + n0 + nf * 16 + col) * C_IN + kc * 32 + quad * 8];
        #pragma unroll
        for (int rs = 0; rs < 3; ++rs) {
            bf16x8 afr = *(const bf16x8*)&wbf[(size_t)(rw + rs * 16 + col) * 256 + kc * 32 + quad * 8];
            #pragma unroll
            for (int nf = 0; nf < 4; ++nf)
                acc[rs][nf] = __builtin_amdgcn_mfma_f32_16x16x32_bf16(afr, bfr[nf], acc[rs][nf], 0, 0, 0);
        }
    }

    // ---- bias + restage C to LDS cl[n][r] ----
    #pragma unroll
    for (int rs = 0; rs < 3; ++rs) {
        int r0 = rw + rs * 16 + quad * 4;
        float b0 = canon[131072 + r0 + 0];
        float b1 = canon[131072 + r0 + 1];
        float b2 = canon[131072 + r0 + 2];
        float b3 = canon[131072 + r0 + 3];
        #pragma unroll
        for (int nf = 0; nf < 4; ++nf) {
            int n = nf * 16 + col;
            uint2 pv;
            pv.x = packbf(acc[rs][nf][0] + b0, acc[rs][nf][1] + b1);
            pv.y = packbf(acc[rs][nf][2] + b2, acc[rs][nf][3] + b3);
            *(uint2*)&plds[n * 400 + r0] = pv;
        }
    }
    __syncthreads();

    {
        int r = tid & 127, nq = tid >> 7;
        u16 tmp[16];
        #pragma unroll
        for (int j = 0; j < 16; ++j) tmp[j] = plds[(nq * 16 + j) * 400 + r];
        u16* dst = &gbuf[((size_t)b * CI_ + r) * N_TOK + n0 + nq * 16];
        *(uint4*)(dst + 0) = *(uint4*)&tmp[0];
        *(uint4*)(dst + 8) = *(uint4*)&tmp[8];
    }
    {
        int n = tid & 63, part = tid >> 6;
        const u16* src = (part < 4) ? &plds[n * 400 + 128 + part * 32]
                                    : &plds[n * 400 + 256 + (part - 4) * 32];
        u16* dst = (part < 4) ? &tbufT[(bN + n0 + n) * CI_ + part * 32]
                              : &pbufT[(bN + n0 + n) * CI_ + (part - 4) * 32];
        #pragma unroll
        for (int v = 0; v < 4; ++v) *(uint4*)(dst + v * 8) = *(const uint4*)(src + v * 8);
    }
}

// =====================================================================
// Kernel B: MFMA flash attention, 4 waves (2 q-waves x 2 m-parities),
// q-tile 32, TM=32/parity, 64 iters. LDS 69888 B -> 2 blocks/CU so two
// blocks' phases interleave (barrier-independent). DMA double-buffered
// staging, fused outproj + bucketed BN-stats epilogue.
// LDS map: Ph [2buf x 2par x 32m x 256B] @0 (32KB);
//          G  [2buf x 2par x 128c x 64B] @32768 (32KB);
//          PB 4 x 1KB @65536; MST @69632; LST @69760; total 69888.
// =====================================================================
#define PH3   0
#define G3    32768
#define PB3   65536
#define MST3  69632
#define LST3  69760
#define SMEM3 69888

__global__ __launch_bounds__(256) void attn_kernel(
    const u16* __restrict__ tbufT, const u16* __restrict__ pbufT,
    const u16* __restrict__ gbuf,
    const u16* __restrict__ wbf, const float* __restrict__ canon,
    u16* __restrict__ wyb, float* __restrict__ stats)
{
    __shared__ __align__(16) char smem[SMEM3];
    const int b   = blockIdx.y;
    const int q0  = blockIdx.x * 32;
    const int tid = threadIdx.x;
    const int w    = tid >> 6;      // 0..3
    const int lane = tid & 63;
    const int col  = lane & 15;
    const int quad = lane >> 4;
    const int wq   = w & 1;         // q-wave
    const int ms   = w >> 1;        // m-parity
    const int qw   = wq * 16;
    const size_t bN = (size_t)b * N_TOK;
    const size_t bC = (size_t)b * CI_;

    bf16x8 thf[4];
    {
        const u16* tb = tbufT + (bN + q0 + qw + col) * CI_;
        #pragma unroll
        for (int kc = 0; kc < 4; ++kc)
            thf[kc] = *(const bf16x8*)(tb + kc * 32 + quad * 8);
    }

    // ---- DMA descriptors: waves 0-1 stage Ph (64 m-rows), waves 2-3 stage G ----
    const u16* sb[8];
    int ldso[8];
    int sstep;
    if (w < 2) {
        int r = lane >> 4, cp = lane & 15;      // 4 rows x 16 chunks per DMA
        sstep = 64 * CI_;
        #pragma unroll
        for (int j = 0; j < 8; ++j) {
            int seg = w * 8 + j;                // 0..15
            int par = seg >> 3, m0 = (seg & 7) * 4;
            int m = m0 + r;
            sb[j] = pbufT + (bN + par * 32 + m) * CI_ + (cp ^ (m & 15)) * 8;
            ldso[j] = PH3 + par * 8192 + m0 * 256;
        }
    } else {
        int r = lane >> 2, cp = lane & 3;       // 16 rows x 4 chunks per DMA
        sstep = 64;
        #pragma unroll
        for (int j = 0; j < 8; ++j) {
            int seg = (w - 2) * 8 + j;          // 0..15
            int par = seg >> 3, c0 = (seg & 7) * 16;
            int c = c0 + r;
            sb[j] = gbuf + (bC + c) * N_TOK + par * 32 + (cp ^ ((c >> 1) & 3)) * 8;
            ldso[j] = G3 + par * 8192 + c0 * 64;
        }
    }

    f32x4 yacc[8];
    #pragma unroll
    for (int i = 0; i < 8; ++i) yacc[i] = (f32x4){0.f, 0.f, 0.f, 0.f};
    float m_st = -3.0e38f, l_st = 0.f;

    // prologue: tile 0 -> buf 0
    #pragma unroll
    for (int j = 0; j < 8; ++j) dma16(sb[j], smem + ldso[j]);

    for (int s = 0; s < 64; ++s) {
        const int bb = (s & 1) << 14;
        __asm volatile("s_waitcnt lgkmcnt(0)" ::: "memory");
        __asm volatile("s_barrier" ::: "memory");
        if (s < 63) {
            const int nb = ((s + 1) & 1) << 14;
            const size_t so = (size_t)(s + 1) * sstep;
            #pragma unroll
            for (int j = 0; j < 8; ++j) dma16(sb[j] + so, smem + nb + ldso[j]);
            __asm volatile("s_waitcnt vmcnt(8)" ::: "memory");
        } else {
            __asm volatile("s_waitcnt vmcnt(0)" ::: "memory");
        }
        __asm volatile("s_barrier" ::: "memory");

        // ---- S^T = PhT . theta (parity ms, 32 m) ----
        f32x4 sacc[2];
        sacc[0] = (f32x4){0.f, 0.f, 0.f, 0.f};
        sacc[1] = (f32x4){0.f, 0.f, 0.f, 0.f};
        #pragma unroll
        for (int kc = 0; kc < 4; ++kc) {
            #pragma unroll
            for (int msub = 0; msub < 2; ++msub) {
                int m = msub * 16 + col;
                int h = kc * 4 + quad;
                bf16x8 af = *(const bf16x8*)(smem + PH3 + bb + ms * 8192 + m * 256 + ((h ^ (m & 15)) << 4));
                sacc[msub] = __builtin_amdgcn_mfma_f32_16x16x32_bf16(af, thf[kc], sacc[msub], 0, 0, 0);
            }
        }

        // ---- online softmax over m ----
        float tmax = sacc[0][0];
        #pragma unroll
        for (int i = 0; i < 2; ++i)
            #pragma unroll
            for (int r = 0; r < 4; ++r) tmax = fmaxf(tmax, sacc[i][r]);
        tmax = fmaxf(tmax, __shfl_xor(tmax, 16));
        tmax = fmaxf(tmax, __shfl_xor(tmax, 32));
        float m_new = fmaxf(m_st, tmax);
        float p16[8], ps = 0.f;
        #pragma unroll
        for (int i = 0; i < 2; ++i)
            #pragma unroll
            for (int r = 0; r < 4; ++r) {
                float pv = __expf(sacc[i][r] - m_new);
                p16[i * 4 + r] = pv;
                ps += pv;
            }
        ps += __shfl_xor(ps, 16);
        ps += __shfl_xor(ps, 32);
        float alpha = __expf(m_st - m_new);
        l_st = l_st * alpha + ps;
        m_st = m_new;
        #pragma unroll
        for (int i = 0; i < 8; ++i) {
            yacc[i][0] *= alpha; yacc[i][1] *= alpha;
            yacc[i][2] *= alpha; yacc[i][3] *= alpha;
        }

        // ---- pack P^T -> per-wave LDS [16 q][32 m], 64B rows ----
        {
            char* pb = smem + PB3 + w * 1024 + col * 64;
            const int swz = (col >> 1) & 3;
            #pragma unroll
            for (int msub = 0; msub < 2; ++msub) {
                #pragma unroll
                for (int pr = 0; pr < 2; ++pr) {
                    u32 d = packbf(p16[msub * 4 + pr * 2], p16[msub * 4 + pr * 2 + 1]);
                    int hl = msub * 2 + (quad >> 1);
                    *(u32*)(pb + ((hl ^ swz) << 4) + (quad & 1) * 8 + pr * 4) = d;
                }
            }
        }
        __asm volatile("s_waitcnt lgkmcnt(0)" ::: "memory");

        // ---- PV: y^T[c][q] += G . P^T (K = 32) ----
        bf16x8 pf = *(const bf16x8*)(smem + PB3 + w * 1024 + col * 64 + ((quad ^ ((col >> 1) & 3)) << 4));
        #pragma unroll
        for (int csub = 0; csub < 8; ++csub) {
            int c = csub * 16 + col;
            bf16x8 gf = *(const bf16x8*)(smem + G3 + bb + ms * 8192 + c * 64 + ((quad ^ ((c >> 1) & 3)) << 4));
            yacc[csub] = __builtin_amdgcn_mfma_f32_16x16x32_bf16(gf, pf, yacc[csub], 0, 0, 0);
        }
    }

    // ---- merge m-parity partials (waves w, w+2); y -> LDS yB ----
    __syncthreads();
    if (ms == 1) {
        char* mb = smem + wq * 8192 + col * 512;
        #pragma unroll
        for (int csub = 0; csub < 8; ++csub)
            *(f32x4*)(mb + (((csub * 4 + quad) ^ col) << 4)) = yacc[csub];
        if (quad == 0) {
            *(float*)(smem + MST3 + (qw + col) * 4) = m_st;
            *(float*)(smem + LST3 + (qw + col) * 4) = l_st;
        }
    }
    __syncthreads();
    if (ms == 0) {
        float m1 = *(const float*)(smem + MST3 + (qw + col) * 4);
        float l1 = *(const float*)(smem + LST3 + (qw + col) * 4);
        float M  = fmaxf(m_st, m1);
        float a0 = __expf(m_st - M), a1 = __expf(m1 - M);
        float li = 1.f / (l_st * a0 + l1 * a1);
        float s0 = a0 * li, s1 = a1 * li;
        const char* mb = smem + wq * 8192 + col * 512;
        const int q = qw + col;
        #pragma unroll
        for (int csub = 0; csub < 8; ++csub) {
            f32x4 y1 = *(const f32x4*)(mb + (((csub * 4 + quad) ^ col) << 4));
            uint2 pv;
            pv.x = packbf(yacc[csub][0] * s0 + y1[0] * s1, yacc[csub][1] * s0 + y1[1] * s1);
            pv.y = packbf(yacc[csub][2] * s0 + y1[2] * s1, yacc[csub][3] * s0 + y1[3] * s1);
            int chunk = csub * 2 + (quad >> 1);
            *(uint2*)(smem + 32768 + q * 256 + ((chunk ^ (q & 15)) << 4) + (quad & 1) * 8) = pv;
        }
    }
    __syncthreads();

    // ---- fused outproj: W_y[o][q] = sum_c wo[o][c] * y[c][q] + bo ----
    const u16* wo = wbf + 98304;
    f32x4 oacc[4][2];
    #pragma unroll
    for (int i = 0; i < 4; ++i) {
        oacc[i][0] = (f32x4){0.f,0.f,0.f,0.f};
        oacc[i][1] = (f32x4){0.f,0.f,0.f,0.f};
    }
    #pragma unroll
    for (int kc = 0; kc < 4; ++kc) {
        bf16x8 bqf[2];
        #pragma unroll
        for (int qf = 0; qf < 2; ++qf) {
            int q = qf * 16 + col;
            int h = kc * 4 + quad;
            bqf[qf] = *(const bf16x8*)(smem + 32768 + q * 256 + ((h ^ (q & 15)) << 4));
        }
        #pragma unroll
        for (int os = 0; os < 4; ++os) {
            bf16x8 afr = *(const bf16x8*)&wo[(size_t)(w * 64 + os * 16 + col) * CI_ + kc * 32 + quad * 8];
            #pragma unroll
            for (int qf = 0; qf < 2; ++qf)
                oacc[os][qf] = __builtin_amdgcn_mfma_f32_16x16x32_bf16(afr, bqf[qf], oacc[os][qf], 0, 0, 0);
        }
    }
    const int bucket = (blockIdx.x + blockIdx.y) & 15;
    float* sbk = stats + bucket * 512;
    #pragma unroll
    for (int os = 0; os < 4; ++os) {
        int ob = w * 64 + os * 16 + quad * 4;
        #pragma unroll
        for (int i = 0; i < 4; ++i) {
            float bb2 = canon[131456 + ob + i];
            float s1 = 0.f, s2 = 0.f;
            u16* dst = &wyb[((size_t)b * C_IN + ob + i) * N_TOK + q0 + col];
            #pragma unroll
            for (int qf = 0; qf < 2; ++qf) {
                float v = oacc[os][qf][i] + bb2;
                dst[qf * 16] = f2bf(v);
                s1 += v;
                s2 += v * v;
            }
            #pragma unroll
            for (int off = 8; off; off >>= 1) {
                s1 += __shfl_xor(s1, off);
                s2 += __shfl_xor(s2, off);
            }
            if (col == 0) {
                atomicAdd(&sbk[ob + i], s1);
                atomicAdd(&sbk[256 + ob + i], s2);
            }
        }
    }
}

// ===================== BN apply + residual =====================
__global__ __launch_bounds__(256) void bnorm_kernel(
    const u16* __restrict__ wyb, const void* __restrict__ x,
    const float* __restrict__ stats,
    const float* __restrict__ canon, const int* __restrict__ flagp,
    void* __restrict__ outv)
{
    const int flag = *flagp;
    size_t base = ((size_t)blockIdx.x * 256 + threadIdx.x) * 8;
    int o = (int)((base >> 12) & 255);
    float sum1 = 0.f, sum2 = 0.f;
    #pragma unroll
    for (int k = 0; k < 16; ++k) {
        sum1 += stats[k * 512 + o];
        sum2 += stats[k * 512 + 256 + o];
    }
    float mean = sum1 * (1.f / 16384.f);
    float var  = sum2 * (1.f / 16384.f) - mean * mean;
    float r = rsqrtf(var + 1e-5f);
    float gm = canon[131712 + o], bt = canon[131968 + o];
    uint4 wu = *(const uint4*)&wyb[base];
    float wv[8]; bf8f(wu, wv);
    float xf[8]; load8(x, base, flag, xf);
    float ov[8];
    #pragma unroll
    for (int i = 0; i < 8; ++i)
        ov[i] = (wv[i] - mean) * r * gm + bt + xf[i];
    if (flag) {
        float* op = (float*)outv + base;
        *(float4*)op       = *(float4*)&ov[0];
        *(float4*)(op + 4) = *(float4*)&ov[4];
    } else {
        uint4 res;
        res.x = packbf(ov[0], ov[1]);
        res.y = packbf(ov[2], ov[3]);
        res.z = packbf(ov[4], ov[5]);
        res.w = packbf(ov[6], ov[7]);
        *(uint4*)((u16*)outv + base) = res;
    }
}

extern "C" void kernel_launch(void* const* d_in, const int* in_sizes, int n_in,
                              void* d_out, int out_size, void* d_ws, size_t ws_size,
                              hipStream_t stream)
{
    const void* x   = d_in[0];
    const void* w_g = d_in[1];
    const void* b_g = d_in[2];
    const void* w_t = d_in[3];
    const void* b_t = d_in[4];
    const void* w_p = d_in[5];
    const void* b_p = d_in[6];
    const void* w_o = d_in[7];
    const void* b_o = d_in[8];
    const void* gm  = d_in[9];
    const void* bt  = d_in[10];

    char* base = (char*)d_ws;
    float* canon    = (float*)base;                    // 132224 f32
    u16*   canon_bf = (u16*)(base + 528896);           // 131072 u16
    int*   flagp    = (int*)(base + 791040);
    float* stats    = (float*)(base + 791296);         // 16 buckets x 512 f32 = 32 KB
    u16*   gbuf     = (u16*)(base + 1048576);          // 4 MB bf16 [b][c][n]
    u16*   tbufT    = (u16*)(base + 5242880);          // 4 MB bf16 [b][n][c]
    u16*   pbufT    = (u16*)(base + 9437184);          // 4 MB bf16 [b][n][c]
    u16*   wyb      = (u16*)(base + 13631488);         // 8 MB bf16 [b][o][n]
    u16*   xbfT     = (u16*)(base + 22020096);         // 8 MB bf16 [b][n][k]

    convert_params_kernel<<<549, 256, 0, stream>>>(w_g, w_t, w_p, w_o, b_g, b_t, b_p, b_o,
                                                   gm, bt, flagp, canon, canon_bf, stats);
    xpose_kernel<<<dim3(64, 4, 4), 256, 0, stream>>>(x, flagp, xbfT);
    proj_kernel<<<dim3(64, 4), 512, 0, stream>>>(xbfT, canon, canon_bf, gbuf, tbufT, pbufT);
    attn_kernel<<<dim3(128, 4), 256, 0, stream>>>(tbufT, pbufT, gbuf, canon_bf, canon, wyb, stats);
    bnorm_kernel<<<2048, 256, 0, stream>>>(wyb, x, stats, canon, flagp, d_out);
}